// Round 3
// baseline (611.499 us; speedup 1.0000x reference)
//
#include <hip/hip_runtime.h>
#include <cstdint>

#define WID   160
#define HEI   160
#define HWPIX (WID * HEI)   // 25600
#define CIN_  64
#define COUT_ 64
#define BATCH 32
#define PW    162           // padded width/height of global packed layout
#define PPIX  (PW * PW)     // 26244
#define NBORDER 636         // 2*160 + 2*158 border pixels per image
#define TR    8             // output rows per block (fused kernel)
#define TLROWS (TR + 2)     // LDS rows incl. halo

// ---------------------------------------------------------------------------
// Kernel 1: weight prep. One wave per output channel. lane = ci.
// wpack[co][tap] bit ci = (w>0); alpha[co] = mean(|clip(w,-1,1)|).
// ---------------------------------------------------------------------------
__global__ __launch_bounds__(64) void wprep_kernel(const float* __restrict__ w,
                                                   uint64_t* __restrict__ wpack,
                                                   float* __restrict__ alpha) {
    const int co = blockIdx.x;
    const int ci = threadIdx.x;
    const float* wp = w + ((size_t)co * CIN_ + ci) * 9;

    float vals[9];
    float s = 0.0f;
#pragma unroll
    for (int t = 0; t < 9; ++t) {
        float v = wp[t];
        vals[t] = v;
        s += fminf(fabsf(v), 1.0f);
    }
#pragma unroll
    for (int t = 0; t < 9; ++t) {
        unsigned long long m = __ballot(vals[t] > 0.0f);
        if (ci == 0) wpack[co * 9 + t] = m;
    }
#pragma unroll
    for (int off = 32; off > 0; off >>= 1) s += __shfl_down(s, off);
    if (ci == 0) alpha[co] = s * (1.0f / 576.0f);
}

// ---------------------------------------------------------------------------
// Kernel 2 (FUSED binpack+conv). Block = (image b, 8-row tile). Phase 1 packs
// rows y0-1..y0+8 into a zeroed LDS tile [10][162] (zero halo = pad) and also
// stores the 8 OWNED rows to global packed (for the fixup kernel; packed's
// border cells are never value-read by fixup, so no memset needed). Phase 2
// convolves the 8 owned rows from LDS: thread = 4 consecutive pixels, loops
// all 64 co with wave-uniform weight s_loads, float4 coalesced stores.
// Border ring output here uses the zero-pad formula (wrong) and is then
// overwritten by fixup_kernel. Co-resident blocks overlap phase-1 (memory)
// with phase-2 (VALU+store) across the CU.
// ---------------------------------------------------------------------------
__global__ __launch_bounds__(320) void bconv_kernel(const float* __restrict__ x,
                                                    const uint64_t* __restrict__ wpack,
                                                    const float* __restrict__ alpha,
                                                    uint64_t* __restrict__ packed,
                                                    float* __restrict__ out) {
    __shared__ uint64_t lds[TLROWS][PW];   // 10*162*8 = 12960 B
    const int tid = threadIdx.x;           // 0..319
    const int b   = blockIdx.y;
    const int y0  = blockIdx.x * TR;

    // zero the tile (halo rows / border cols act as the zero pad)
    for (int i = tid; i < TLROWS * PW; i += 320)
        ((uint64_t*)lds)[i] = 0;
    __syncthreads();

    // ---- phase 1: binpack 10 rows x 40 four-pixel groups = 400 groups ----
    for (int g = tid; g < TLROWS * 40; g += 320) {
        const int rr = g / 40;             // LDS row 0..9
        const int yy = y0 + rr - 1;        // image row
        if (yy >= 0 && yy < HEI) {
            const int x4 = (g - rr * 40) * 4;
            const float4* xp = (const float4*)(x + (size_t)b * CIN_ * HWPIX
                                                 + (size_t)yy * WID + x4);
            uint32_t lo[4] = {0, 0, 0, 0}, hi[4] = {0, 0, 0, 0};
#pragma unroll
            for (int ci = 0; ci < 32; ++ci) {
                float4 v = xp[(size_t)ci * (HWPIX / 4)];
                lo[0] |= (uint32_t)(v.x > 0.0f) << ci;
                lo[1] |= (uint32_t)(v.y > 0.0f) << ci;
                lo[2] |= (uint32_t)(v.z > 0.0f) << ci;
                lo[3] |= (uint32_t)(v.w > 0.0f) << ci;
            }
#pragma unroll
            for (int ci = 0; ci < 32; ++ci) {
                float4 v = xp[(size_t)(ci + 32) * (HWPIX / 4)];
                hi[0] |= (uint32_t)(v.x > 0.0f) << ci;
                hi[1] |= (uint32_t)(v.y > 0.0f) << ci;
                hi[2] |= (uint32_t)(v.z > 0.0f) << ci;
                hi[3] |= (uint32_t)(v.w > 0.0f) << ci;
            }
            uint64_t w4[4];
#pragma unroll
            for (int i = 0; i < 4; ++i)
                w4[i] = ((uint64_t)hi[i] << 32) | lo[i];
#pragma unroll
            for (int i = 0; i < 4; ++i)
                lds[rr][x4 + 1 + i] = w4[i];           // LDS col c = padded col c
            if (rr >= 1 && rr <= TR) {                 // owned row -> global packed
                uint64_t* dst = packed + (size_t)b * PPIX
                              + (size_t)(yy + 1) * PW + (x4 + 1);
#pragma unroll
                for (int i = 0; i < 4; ++i) dst[i] = w4[i];
            }
        }
    }
    __syncthreads();

    // ---- phase 2: conv 8 rows x 40 groups = 320 groups, one per thread ----
    const int r  = tid / 40;               // 0..7 within tile
    const int x4 = (tid - r * 40) * 4;     // x in {0,4,...,156}
    const int y  = y0 + r;

    // top-left tap of pixel (y, x4) is LDS[r][x4]; 3 rows x 6 cols cover all 4 px
    uint64_t p[3][6];
#pragma unroll
    for (int ky = 0; ky < 3; ++ky)
#pragma unroll
        for (int kx = 0; kx < 6; ++kx)
            p[ky][kx] = lds[r + ky][x4 + kx];

    float* op = out + (size_t)b * COUT_ * HWPIX + (size_t)y * WID + x4;
#pragma unroll 4
    for (int co = 0; co < COUT_; ++co) {
        const uint64_t* wp = wpack + co * 9;
        int pc0 = 0, pc1 = 0, pc2 = 0, pc3 = 0;
#pragma unroll
        for (int ky = 0; ky < 3; ++ky)
#pragma unroll
            for (int kx = 0; kx < 3; ++kx) {
                const uint64_t ww = wp[ky * 3 + kx];   // wave-uniform -> s_load
                pc0 += __popcll(p[ky][kx + 0] ^ ww);
                pc1 += __popcll(p[ky][kx + 1] ^ ww);
                pc2 += __popcll(p[ky][kx + 2] ^ ww);
                pc3 += __popcll(p[ky][kx + 3] ^ ww);
            }
        const float a = alpha[co];
        const float c = 576.0f * a;
        const float m = -2.0f * a;
        float4 rv;
        rv.x = fmaf((float)pc0, m, c);
        rv.y = fmaf((float)pc1, m, c);
        rv.z = fmaf((float)pc2, m, c);
        rv.w = fmaf((float)pc3, m, c);
        *(float4*)(op + (size_t)co * HWPIX) = rv;      // 16B-aligned, coalesced
    }
}

// ---------------------------------------------------------------------------
// Kernel 3: exact recompute of the 636-pixel border ring (valid taps only).
// Reads global packed interior cells only (invalid-tap reads are in-bounds
// but value-irrelevant), so packed borders may hold workspace poison.
// ---------------------------------------------------------------------------
__global__ __launch_bounds__(256) void fixup_kernel(const uint64_t* __restrict__ packed,
                                                    const uint64_t* __restrict__ wpack,
                                                    const float* __restrict__ alpha,
                                                    float* __restrict__ out) {
    const int t = blockIdx.x * 256 + threadIdx.x;
    if (t >= NBORDER * BATCH) return;
    const int b = t / NBORDER;
    const int i = t - b * NBORDER;
    int x, y;
    if      (i < 160) { y = 0;       x = i;       }
    else if (i < 320) { y = 159;     x = i - 160; }
    else if (i < 478) { x = 0;       y = i - 319; }  // y = 1..158
    else              { x = 159;     y = i - 477; }  // y = 1..158

    const uint64_t* pb = packed + (size_t)b * PPIX + (size_t)y * PW + x;
    uint64_t p[9];
    int valid[9];
    int nv = 0;
#pragma unroll
    for (int ky = 0; ky < 3; ++ky)
#pragma unroll
        for (int kx = 0; kx < 3; ++kx) {
            const int yy = y + ky - 1, xx = x + kx - 1;
            const int v = (yy >= 0) && (yy < HEI) && (xx >= 0) && (xx < WID);
            valid[ky * 3 + kx] = v;
            nv += v;
            p[ky * 3 + kx] = pb[(size_t)ky * PW + kx];  // in-bounds; value used only if valid
        }
    float* op = out + (size_t)b * COUT_ * HWPIX + (size_t)y * WID + x;
    for (int co = 0; co < COUT_; ++co) {
        int pc = 0;
#pragma unroll
        for (int tt = 0; tt < 9; ++tt)
            pc += valid[tt] ? __popcll(p[tt] ^ wpack[co * 9 + tt]) : 0;
        op[(size_t)co * HWPIX] = alpha[co] * (float)((nv << 6) - 2 * pc);
    }
}

// ---------------------------------------------------------------------------
extern "C" void kernel_launch(void* const* d_in, const int* in_sizes, int n_in,
                              void* d_out, int out_size, void* d_ws, size_t ws_size,
                              hipStream_t stream) {
    const float* x = (const float*)d_in[0];  // [32,64,160,160] f32
    const float* w = (const float*)d_in[1];  // [64,64,3,3] f32
    float* out = (float*)d_out;              // [32,64,160,160] f32

    uint64_t* wpack  = (uint64_t*)d_ws;                      // 4608 B
    float*    alpha  = (float*)((char*)d_ws + 4608);         // 256 B
    uint64_t* packed = (uint64_t*)((char*)d_ws + 8192);      // 32*26244*8 = 6.72 MB

    // no memset: bconv writes all interior packed cells; fixup never
    // value-reads border cells (valid-masked), poison there is harmless.

    wprep_kernel<<<dim3(COUT_), dim3(64), 0, stream>>>(w, wpack, alpha);
    bconv_kernel<<<dim3(HEI / TR, BATCH), dim3(320), 0, stream>>>(x, wpack, alpha, packed, out);
    fixup_kernel<<<dim3((NBORDER * BATCH + 255) / 256), dim3(256), 0, stream>>>(packed, wpack, alpha, out);
}

// Round 4
// 437.932 us; speedup vs baseline: 1.3963x; 1.3963x over previous
//
#include <hip/hip_runtime.h>
#include <cstdint>

#define WID   160
#define HEI   160
#define HWPIX (WID * HEI)   // 25600
#define CIN_  64
#define COUT_ 64
#define BATCH 32
#define PW    162           // padded width/height (zero border)
#define PPIX  (PW * PW)     // 26244
#define NBORDER 636         // 2*160 + 2*158 border pixels per image

// ---------------------------------------------------------------------------
// Kernel 1: weight prep. One wave per output channel. lane = ci.
// wpack[co][tap] bit ci = (w>0); alpha[co] = mean(|clip(w,-1,1)|).
// ---------------------------------------------------------------------------
__global__ __launch_bounds__(64) void wprep_kernel(const float* __restrict__ w,
                                                   uint64_t* __restrict__ wpack,
                                                   float* __restrict__ alpha) {
    const int co = blockIdx.x;
    const int ci = threadIdx.x;
    const float* wp = w + ((size_t)co * CIN_ + ci) * 9;

    float vals[9];
    float s = 0.0f;
#pragma unroll
    for (int t = 0; t < 9; ++t) {
        float v = wp[t];
        vals[t] = v;
        s += fminf(fabsf(v), 1.0f);
    }
#pragma unroll
    for (int t = 0; t < 9; ++t) {
        unsigned long long m = __ballot(vals[t] > 0.0f);
        if (ci == 0) wpack[co * 9 + t] = m;
    }
#pragma unroll
    for (int off = 32; off > 0; off >>= 1) s += __shfl_down(s, off);
    if (ci == 0) alpha[co] = s * (1.0f / 576.0f);
}

// ---------------------------------------------------------------------------
// Kernel 2: binarize + channel-pack into zero-padded [b][162][162] u64 layout.
// Thread = 4 consecutive pixels (160%4==0 -> never crosses a row). float4 loads.
// Block 0 of each image also zeroes the 644 border cells (replaces memset).
// ---------------------------------------------------------------------------
__global__ __launch_bounds__(256) void binpack_kernel(const float* __restrict__ x,
                                                      uint64_t* __restrict__ packed) {
    const int t  = blockIdx.x * 256 + threadIdx.x;   // 0..6399
    const int b  = blockIdx.y;
    uint64_t* pimg = packed + (size_t)b * PPIX;

    // border zeroing: rows 0 and 161 (162 cells each), cols 0 and 161 (160 each)
    if (blockIdx.x == 0) {
        for (int j = threadIdx.x; j < PW; j += 256) {
            pimg[j] = 0;                              // top padded row
            pimg[(size_t)(PW - 1) * PW + j] = 0;      // bottom padded row
        }
        for (int r = threadIdx.x; r < HEI; r += 256) {
            pimg[(size_t)(r + 1) * PW] = 0;           // left padded col
            pimg[(size_t)(r + 1) * PW + (PW - 1)] = 0;// right padded col
        }
    }

    const int p4 = t * 4;
    const int y  = p4 / WID;
    const int x0 = p4 - y * WID;
    const float4* xp = (const float4*)(x + (size_t)b * CIN_ * HWPIX + p4);

    uint32_t lo[4] = {0, 0, 0, 0}, hi[4] = {0, 0, 0, 0};
#pragma unroll
    for (int ci = 0; ci < 32; ++ci) {
        float4 v = xp[(size_t)ci * (HWPIX / 4)];
        lo[0] |= (uint32_t)(v.x > 0.0f) << ci;
        lo[1] |= (uint32_t)(v.y > 0.0f) << ci;
        lo[2] |= (uint32_t)(v.z > 0.0f) << ci;
        lo[3] |= (uint32_t)(v.w > 0.0f) << ci;
    }
#pragma unroll
    for (int ci = 0; ci < 32; ++ci) {
        float4 v = xp[(size_t)(ci + 32) * (HWPIX / 4)];
        hi[0] |= (uint32_t)(v.x > 0.0f) << ci;
        hi[1] |= (uint32_t)(v.y > 0.0f) << ci;
        hi[2] |= (uint32_t)(v.z > 0.0f) << ci;
        hi[3] |= (uint32_t)(v.w > 0.0f) << ci;
    }
    uint64_t* dst = pimg + (size_t)(y + 1) * PW + (x0 + 1);
#pragma unroll
    for (int i = 0; i < 4; ++i)
        dst[i] = ((uint64_t)hi[i] << 32) | lo[i];
}

// ---------------------------------------------------------------------------
// Kernel 3: main conv. Thread = FOUR consecutive pixels in one row (x%4==0,
// 16B-aligned float4 store, never crosses a row). Loads the 3x6 padded tap
// window ONCE, loops all 64 co with wave-uniform (scalar) weight loads
// amortized over 4 pixels. No bounds checks (zero pad); border ring is wrong
// here and overwritten by fixup_kernel.
// ---------------------------------------------------------------------------
__global__ __launch_bounds__(256) void conv_kernel(const uint64_t* __restrict__ packed,
                                                   const uint64_t* __restrict__ wpack,
                                                   const float* __restrict__ alpha,
                                                   float* __restrict__ out) {
    const int t4 = blockIdx.x * 256 + threadIdx.x;   // 0..6399 per image
    const int b  = blockIdx.y;
    const int p0 = t4 * 4;                 // first pixel of this thread
    const int y  = p0 / WID;
    const int x  = p0 - y * WID;           // x in {0,4,...,156}
    const uint64_t* pb = packed + (size_t)b * PPIX + (size_t)y * PW + x;

    uint64_t p[3][6];
#pragma unroll
    for (int ky = 0; ky < 3; ++ky)
#pragma unroll
        for (int kx = 0; kx < 6; ++kx)
            p[ky][kx] = pb[(size_t)ky * PW + kx];

    float* op = out + (size_t)b * COUT_ * HWPIX + p0;
#pragma unroll 4
    for (int co = 0; co < COUT_; ++co) {
        const uint64_t* wp = wpack + co * 9;
        int pc0 = 0, pc1 = 0, pc2 = 0, pc3 = 0;
#pragma unroll
        for (int ky = 0; ky < 3; ++ky)
#pragma unroll
            for (int kx = 0; kx < 3; ++kx) {
                const uint64_t ww = wp[ky * 3 + kx];   // wave-uniform -> s_load
                pc0 += __popcll(p[ky][kx + 0] ^ ww);
                pc1 += __popcll(p[ky][kx + 1] ^ ww);
                pc2 += __popcll(p[ky][kx + 2] ^ ww);
                pc3 += __popcll(p[ky][kx + 3] ^ ww);
            }
        const float a = alpha[co];
        const float c = 576.0f * a;
        const float m = -2.0f * a;
        float4 r;
        r.x = fmaf((float)pc0, m, c);
        r.y = fmaf((float)pc1, m, c);
        r.z = fmaf((float)pc2, m, c);
        r.w = fmaf((float)pc3, m, c);
        *(float4*)(op + (size_t)co * HWPIX) = r;       // 16B-aligned, coalesced
    }
}

// ---------------------------------------------------------------------------
// Kernel 4: exact recompute of the 636-pixel border ring, CO-PARALLEL:
// thread = one (border-pixel, co) pair -> 1.30M threads / ~20k waves
// (vs 318 waves before: was a latency-bound serial-co tail).
// blockIdx.y = co (wave-uniform -> weight reads are s_loads).
// ---------------------------------------------------------------------------
__global__ __launch_bounds__(256) void fixup_kernel(const uint64_t* __restrict__ packed,
                                                    const uint64_t* __restrict__ wpack,
                                                    const float* __restrict__ alpha,
                                                    float* __restrict__ out) {
    const int t = blockIdx.x * 256 + threadIdx.x;
    if (t >= NBORDER * BATCH) return;
    const int co = blockIdx.y;
    const int b  = t / NBORDER;
    const int i  = t - b * NBORDER;
    int x, y;
    if      (i < 160) { y = 0;       x = i;       }
    else if (i < 320) { y = 159;     x = i - 160; }
    else if (i < 478) { x = 0;       y = i - 319; }  // y = 1..158
    else              { x = 159;     y = i - 477; }  // y = 1..158

    const uint64_t* pb = packed + (size_t)b * PPIX + (size_t)y * PW + x;
    const uint64_t* wp = wpack + co * 9;
    int pc = 0, nv = 0;
#pragma unroll
    for (int ky = 0; ky < 3; ++ky)
#pragma unroll
        for (int kx = 0; kx < 3; ++kx) {
            const int yy = y + ky - 1, xx = x + kx - 1;
            const int v = (yy >= 0) && (yy < HEI) && (xx >= 0) && (xx < WID);
            const uint64_t pt = pb[(size_t)ky * PW + kx];  // in-bounds (pad ring)
            nv += v;
            pc += v ? __popcll(pt ^ wp[ky * 3 + kx]) : 0;
        }
    out[(size_t)b * COUT_ * HWPIX + (size_t)co * HWPIX + (size_t)y * WID + x] =
        alpha[co] * (float)((nv << 6) - 2 * pc);
}

// ---------------------------------------------------------------------------
extern "C" void kernel_launch(void* const* d_in, const int* in_sizes, int n_in,
                              void* d_out, int out_size, void* d_ws, size_t ws_size,
                              hipStream_t stream) {
    const float* x = (const float*)d_in[0];  // [32,64,160,160] f32
    const float* w = (const float*)d_in[1];  // [64,64,3,3] f32
    float* out = (float*)d_out;              // [32,64,160,160] f32

    uint64_t* wpack  = (uint64_t*)d_ws;                      // 4608 B
    float*    alpha  = (float*)((char*)d_ws + 4608);         // 256 B
    uint64_t* packed = (uint64_t*)((char*)d_ws + 8192);      // 32*26244*8 = 6.72 MB

    // no memset: binpack block 0 zeroes the padded border ring per image.

    wprep_kernel<<<dim3(COUT_), dim3(64), 0, stream>>>(w, wpack, alpha);
    binpack_kernel<<<dim3(HWPIX / 4 / 256, BATCH), dim3(256), 0, stream>>>(x, packed);
    conv_kernel<<<dim3(HWPIX / 4 / 256, BATCH), dim3(256), 0, stream>>>(packed, wpack, alpha, out);
    fixup_kernel<<<dim3((NBORDER * BATCH + 255) / 256, COUT_), dim3(256), 0, stream>>>(packed, wpack, alpha, out);
}